// Round 10
// baseline (803.170 us; speedup 1.0000x reference)
//
#include <hip/hip_runtime.h>

#define N_NODES 20000
#define N_EDGES 160000
#define CH      768
#define CH3     2304
#define NGRAPH  256
#define NCLS    32

typedef __bf16 bf16v8 __attribute__((ext_vector_type(8)));
typedef float  f32x4  __attribute__((ext_vector_type(4)));

// ---------- helpers ----------
__device__ __forceinline__ float b2f(ushort u) {
    union { float f; unsigned u; } x; x.u = ((unsigned)u) << 16; return x.f;
}
__device__ __forceinline__ ushort f2b(float f) {
    union { float f; unsigned u; } x; x.f = f;
    unsigned r = x.u + 0x7FFFu + ((x.u >> 16) & 1u);
    return (ushort)(r >> 16);
}
// permuted 6-ch load: 4ch aligned ushort4 chunk + 2ch ushort2 chunk (one head)
__device__ __forceinline__ void load6u(const ushort* __restrict__ p, int o1, int o2, float* o) {
    ushort4 a = *(const ushort4*)(p + o1);
    ushort2 b = *(const ushort2*)(p + o2);
    o[0]=b2f(a.x); o[1]=b2f(a.y); o[2]=b2f(a.z); o[3]=b2f(a.w);
    o[4]=b2f(b.x); o[5]=b2f(b.y);
}
__device__ __forceinline__ void load6f2(const float* __restrict__ p, int o1, int o2, float* o) {
    float4 a = *(const float4*)(p + o1);
    float2 b = *(const float2*)(p + o2);
    o[0]=a.x; o[1]=a.y; o[2]=a.z; o[3]=a.w; o[4]=b.x; o[5]=b.y;
}
__device__ __forceinline__ void async_copy16(void* lds, const void* gp) {
    __builtin_amdgcn_global_load_lds((const void __attribute__((address_space(1)))*)gp,
                                     (void __attribute__((address_space(3)))*)lds, 16, 0, 0);
}

// ---------- f32 -> bf16 conversion (4-wide) ----------
__global__ void cvt_x_kernel(const float* __restrict__ src, ushort* __restrict__ dst, int n4) {
    int i = blockIdx.x * 256 + threadIdx.x;
    if (i >= n4) return;
    float4 v = ((const float4*)src)[i];
    ushort4 o; o.x = f2b(v.x); o.y = f2b(v.y); o.z = f2b(v.z); o.w = f2b(v.w);
    ((ushort4*)dst)[i] = o;
}

// ---------- all 7 weight transposes (+cvt) in one dispatch: grid (24,24,7) ----------
__global__ void transpose_cvt_all(const float* __restrict__ w_in,
                                  const float* __restrict__ Wl,
                                  const float* __restrict__ Wr,
                                  ushort* __restrict__ wt_in,
                                  ushort* __restrict__ wt_l) {
    __shared__ float tile[32][33];
    int z = blockIdx.z;
    const float* in;
    ushort* out;
    if (z == 0) { in = w_in; out = wt_in; }
    else {
        int l = (z - 1) >> 1, isr = (z - 1) & 1;
        in  = (isr ? Wr : Wl) + (size_t)l * CH * CH;
        out = wt_l + (size_t)l * 1536 * CH + (size_t)isr * CH * CH;
    }
    int bx = blockIdx.x * 32, by = blockIdx.y * 32;
    int tx = threadIdx.x, ty = threadIdx.y;
    #pragma unroll
    for (int i = ty; i < 32; i += 8) tile[i][tx] = in[(size_t)(by + i) * CH + bx + tx];
    __syncthreads();
    #pragma unroll
    for (int i = ty; i < 32; i += 8) out[(size_t)(bx + i) * CH + by + tx] = f2b(tile[tx][i]);
}

// ---------- CSR build ----------
__global__ void count_both_kernel(const int* __restrict__ dst, int* __restrict__ deg, int e,
                                  const int* __restrict__ batch, int* __restrict__ gcount, int n) {
    int i = blockIdx.x * 256 + threadIdx.x;
    if (i < e) atomicAdd(&deg[dst[i]], 1);
    if (i < n) { atomicAdd(&deg[i], 1); atomicAdd(&gcount[batch[i]], 1); }
}
__global__ __launch_bounds__(1024) void scan_kernel(const int* __restrict__ deg,
                                                    int* __restrict__ rowptr, int n) {
    __shared__ int part[1024];
    int t = threadIdx.x;
    const int chunk = (n + 1023) / 1024;
    int base = t * chunk;
    int s = 0;
    for (int i = 0; i < chunk; ++i) { int idx = base + i; if (idx < n) s += deg[idx]; }
    part[t] = s; __syncthreads();
    for (int off = 1; off < 1024; off <<= 1) {
        int v = (t >= off) ? part[t - off] : 0;
        __syncthreads();
        part[t] += v;
        __syncthreads();
    }
    int run = (t == 0) ? 0 : part[t - 1];
    for (int i = 0; i < chunk; ++i) {
        int idx = base + i;
        if (idx < n) { rowptr[idx] = run; run += deg[idx]; }
    }
    if (t == 1023) rowptr[n] = part[1023];
}
__global__ void selfloop_kernel(const int* __restrict__ rowptr, int* __restrict__ csrc,
                                int* __restrict__ cursor, int n) {
    int i = blockIdx.x * 256 + threadIdx.x;
    if (i < n) { int p = rowptr[i]; csrc[p] = i; cursor[i] = p + 1; }
}
__global__ void scatter_kernel(const int* __restrict__ src, const int* __restrict__ dst,
                               int* __restrict__ cursor, int* __restrict__ csrc, int e) {
    int i = blockIdx.x * 256 + threadIdx.x;
    if (i < e) { int p = atomicAdd(&cursor[dst[i]], 1); csrc[p] = src[i]; }
}
__global__ __launch_bounds__(256) void gscan_kernel(const int* __restrict__ gcount,
                                                    int* __restrict__ gstart) {
    __shared__ int p[256];
    int t = threadIdx.x;
    p[t] = gcount[t]; __syncthreads();
    for (int off = 1; off < 256; off <<= 1) {
        int v = (t >= off) ? p[t - off] : 0;
        __syncthreads();
        p[t] += v;
        __syncthreads();
    }
    gstart[t] = p[t] - gcount[t];
    if (t == 255) gstart[256] = p[255];
}

// ---------- GEMM: C = A[M,768] * Bt^T + bias(f32); split-C epilogue:
// cols < nsplit -> Cx (stride ldx), else Cy (stride ldy). ----------
__global__ __launch_bounds__(256) void gemm_bf16_kernel(
    const ushort* __restrict__ A, int lda,
    const ushort* __restrict__ Bt,
    const float* __restrict__ biasA, const float* __restrict__ biasB, int nsplit,
    ushort* __restrict__ Cx, int ldx, ushort* __restrict__ Cy, int ldy, int M) {
    __shared__ __bf16 As[128 * 32];
    __shared__ __bf16 Bs[128 * 32];
    int tid = threadIdx.x;
    int wave = tid >> 6, lane = tid & 63;
    int wr = wave >> 1, wc = wave & 1;

    int bid = blockIdx.y * gridDim.x + blockIdx.x;
    int pf = 8 * gridDim.y;
    int p  = bid / pf;
    int rem = bid - p * pf;
    int rp = min(8, (int)gridDim.x - p * 8);
    int row_t = p * 8 + rem % rp;
    int col_t = rem / rp;
    int row0 = row_t * 128, col0 = col_t * 128;

    int c1 = wave * 64 + lane, c2 = c1 + 256;
    int ar1 = min(row0 + (c1 >> 2), M - 1), ak1 = (c1 & 3) * 8;
    int ar2 = min(row0 + (c2 >> 2), M - 1), ak2 = (c2 & 3) * 8;
    int br1 = col0 + (c1 >> 2), br2 = col0 + (c2 >> 2);
    const ushort* a1 = A + (size_t)ar1 * lda + ak1;
    const ushort* a2 = A + (size_t)ar2 * lda + ak2;
    const ushort* b1 = Bt + (size_t)br1 * CH + ak1;
    const ushort* b2 = Bt + (size_t)br2 * CH + ak2;
    __bf16* asb1 = As + (wave * 64) * 8;
    __bf16* asb2 = As + (256 + wave * 64) * 8;
    __bf16* bsb1 = Bs + (wave * 64) * 8;
    __bf16* bsb2 = Bs + (256 + wave * 64) * 8;

    f32x4 acc[4][4] = {};
    int l16 = lane & 15, lq = lane >> 4;

    for (int k0 = 0; k0 < CH; k0 += 32) {
        async_copy16(asb1, a1 + k0);
        async_copy16(asb2, a2 + k0);
        async_copy16(bsb1, b1 + k0);
        async_copy16(bsb2, b2 + k0);
        __syncthreads();
        bf16v8 av[4], bv[4];
        #pragma unroll
        for (int i = 0; i < 4; ++i)
            av[i] = *(const bf16v8*)(As + ((wr * 64 + i * 16 + l16) * 32 + lq * 8));
        #pragma unroll
        for (int j = 0; j < 4; ++j)
            bv[j] = *(const bf16v8*)(Bs + ((wc * 64 + j * 16 + l16) * 32 + lq * 8));
        #pragma unroll
        for (int i = 0; i < 4; ++i)
            #pragma unroll
            for (int j = 0; j < 4; ++j)
                acc[i][j] = __builtin_amdgcn_mfma_f32_16x16x32_bf16(av[i], bv[j], acc[i][j], 0, 0, 0);
        __syncthreads();
    }
    #pragma unroll
    for (int i = 0; i < 4; ++i) {
        int mbase = row0 + wr * 64 + i * 16 + lq * 4;
        #pragma unroll
        for (int j = 0; j < 4; ++j) {
            int col = col0 + wc * 64 + j * 16 + l16;
            bool isx = (col < nsplit);
            float bb = isx ? biasA[col] : biasB[col - nsplit];
            ushort* base = isx ? Cx : Cy;
            int ld = isx ? ldx : ldy;
            int cc = isx ? col : (col - nsplit);
            #pragma unroll
            for (int r = 0; r < 4; ++r) {
                int mm = mbase + r;
                if (mm < M) base[(size_t)mm * ld + cc] = f2b(acc[i][j][r] + bb);
            }
        }
    }
}

// ---------- fused GATv2 node kernel. Two waves per node; head-aligned
// permuted channel map: each lane holds one ushort4 chunk + one ushort2 chunk
// within a single head -> 2 load instrs / 12 cache lines per row gather
// (was 3 instrs / 36 lines). Gathers hit the dense 30.7MB xl table.
__global__ __launch_bounds__(256) void gat_node_kernel(
    const ushort* __restrict__ xl,            // [N][768] bf16 (gather table)
    const ushort* __restrict__ xrb,           // [N][768] bf16
    const ushort* __restrict__ hin, int ldh,  // residual rows (bf16)
    const int* __restrict__ rowptr, const int* __restrict__ csrc,
    const float* __restrict__ att, const float* __restrict__ gbias,
    const float* __restrict__ lnw, const float* __restrict__ lnb,
    ushort* __restrict__ hout, int nn) {
    __shared__ float sred[2][2][2];   // [node-slot][metric][half]
    int wv = threadIdx.x >> 6, lane = threadIdx.x & 63;
    int slot = wv >> 1, half = wv & 1;
    int n = blockIdx.x * 2 + slot;    // grid exactly nn/2
    int k = lane >> 4, j = lane & 15;
    int head = half * 4 + k;
    int o1 = head * 96 + 4 * j;        // 4-ch chunk (8B aligned)
    int o2 = head * 96 + 64 + 2 * j;   // 2-ch chunk (4B aligned)

    float attv[6], xr[6], acc1[6], acc2[6];
    load6f2(att, o1, o2, attv);
    load6u(xrb + (size_t)n * CH, o1, o2, xr);
    #pragma unroll
    for (int q = 0; q < 6; ++q) { acc1[q] = 0.f; acc2[q] = 0.f; }
    float m1 = -1e30f, s1 = 0.f, m2 = -1e30f, s2 = 0.f;
    int rs = rowptr[n], re = rowptr[n + 1];
    int e = rs;
    for (; e + 1 < re; e += 2) {
        int sa = csrc[e], sb = csrc[e + 1];
        float xa[6], xb[6];
        load6u(xl + (size_t)sa * CH, o1, o2, xa);
        load6u(xl + (size_t)sb * CH, o1, o2, xb);
        float da = 0.f, db = 0.f;
        #pragma unroll
        for (int q = 0; q < 6; ++q) {
            float va = xa[q] + xr[q]; va = (va > 0.f) ? va : 0.2f * va;
            float vb = xb[q] + xr[q]; vb = (vb > 0.f) ? vb : 0.2f * vb;
            da = fmaf(va, attv[q], da);
            db = fmaf(vb, attv[q], db);
        }
        da += __shfl_xor(da, 1); db += __shfl_xor(db, 1);
        da += __shfl_xor(da, 2); db += __shfl_xor(db, 2);
        da += __shfl_xor(da, 4); db += __shfl_xor(db, 4);
        da += __shfl_xor(da, 8); db += __shfl_xor(db, 8);   // 16-lane head logit
        float nm1 = fmaxf(m1, da), nm2 = fmaxf(m2, db);
        float sc1 = __expf(m1 - nm1), sc2 = __expf(m2 - nm2);
        float ex1 = __expf(da - nm1), ex2 = __expf(db - nm2);
        s1 = s1 * sc1 + ex1;
        s2 = s2 * sc2 + ex2;
        #pragma unroll
        for (int q = 0; q < 6; ++q) {
            acc1[q] = fmaf(acc1[q], sc1, ex1 * xa[q]);
            acc2[q] = fmaf(acc2[q], sc2, ex2 * xb[q]);
        }
        m1 = nm1; m2 = nm2;
    }
    if (e < re) {   // odd tail -> chain 1
        int sa = csrc[e];
        float xa[6];
        load6u(xl + (size_t)sa * CH, o1, o2, xa);
        float da = 0.f;
        #pragma unroll
        for (int q = 0; q < 6; ++q) {
            float va = xa[q] + xr[q]; va = (va > 0.f) ? va : 0.2f * va;
            da = fmaf(va, attv[q], da);
        }
        da += __shfl_xor(da, 1);
        da += __shfl_xor(da, 2);
        da += __shfl_xor(da, 4);
        da += __shfl_xor(da, 8);
        float nm = fmaxf(m1, da);
        float sc = __expf(m1 - nm), ex = __expf(da - nm);
        s1 = s1 * sc + ex;
        #pragma unroll
        for (int q = 0; q < 6; ++q) acc1[q] = fmaf(acc1[q], sc, ex * xa[q]);
        m1 = nm;
    }
    // merge the two chains
    float M = fmaxf(m1, m2);
    float w1 = __expf(m1 - M), w2 = __expf(m2 - M);
    float inv = 1.f / (s1 * w1 + s2 * w2);
    float hres[6], gb[6], tv[6];
    load6u(hin + (size_t)n * ldh, o1, o2, hres);
    load6f2(gbias, o1, o2, gb);
    float lsum = 0.f, lsq = 0.f;
    #pragma unroll
    for (int q = 0; q < 6; ++q) {
        tv[q] = (acc1[q] * w1 + acc2[q] * w2) * inv + gb[q] + hres[q];
        lsum += tv[q];
        lsq = fmaf(tv[q], tv[q], lsq);
    }
    #pragma unroll
    for (int o = 1; o < 64; o <<= 1) { lsum += __shfl_xor(lsum, o); lsq += __shfl_xor(lsq, o); }
    if (lane == 0) { sred[slot][0][half] = lsum; sred[slot][1][half] = lsq; }
    __syncthreads();
    float S = sred[slot][0][0] + sred[slot][0][1];
    float Q = sred[slot][1][0] + sred[slot][1][1];
    float mu = S * (1.f / 768.f);
    float var = Q * (1.f / 768.f) - mu * mu;
    float rstd = rsqrtf(var + 1e-5f);
    float wv6[6], bv6[6];
    load6f2(lnw, o1, o2, wv6);
    load6f2(lnb, o1, o2, bv6);
    float g[6];
    #pragma unroll
    for (int q = 0; q < 6; ++q) {
        float y = (tv[q] - mu) * rstd * wv6[q] + bv6[q];
        g[q] = 0.5f * y * (1.f + erff(y * 0.70710678118f));
    }
    ushort* op = hout + (size_t)n * CH3;
    ushort4 u; u.x = f2b(g[0]); u.y = f2b(g[1]); u.z = f2b(g[2]); u.w = f2b(g[3]);
    ushort2 v; v.x = f2b(g[4]); v.y = f2b(g[5]);
    *(ushort4*)(op + o1) = u;
    *(ushort2*)(op + o2) = v;
}

// ---------- global mean pool: 4 independent accumulators ----------
__global__ __launch_bounds__(256) void pool_kernel(const ushort* __restrict__ hc,
                                                   const int* __restrict__ gstart,
                                                   float* __restrict__ pooled) {
    int g = blockIdx.x;
    int c = blockIdx.y * 256 + threadIdx.x;
    int s = gstart[g], e = gstart[g + 1];
    const ushort* p = hc + (size_t)s * CH3 + c;
    float a0 = 0.f, a1 = 0.f, a2 = 0.f, a3 = 0.f;
    int n = s;
    for (; n + 3 < e; n += 4) {
        a0 += b2f(p[0]);
        a1 += b2f(p[CH3]);
        a2 += b2f(p[2 * CH3]);
        a3 += b2f(p[3 * CH3]);
        p += 4 * CH3;
    }
    for (; n < e; ++n) { a0 += b2f(*p); p += CH3; }
    float a = (a0 + a1) + (a2 + a3);
    pooled[(size_t)g * CH3 + c] = a * (1.f / (float)max(e - s, 1));
}

// ---------- final LN + [2304x32] matmul (all f32) ----------
__global__ __launch_bounds__(256) void head_kernel(const float* __restrict__ pooled,
                                                   const float* __restrict__ olnw,
                                                   const float* __restrict__ olnb,
                                                   const float* __restrict__ wout,
                                                   const float* __restrict__ bout,
                                                   float* __restrict__ outp) {
    __shared__ float row[CH3];
    __shared__ float red[8];
    __shared__ float parts[8][32];
    int g = blockIdx.x, t = threadIdx.x;
    int lane = t & 63, wv = t >> 6;
    float s = 0.f;
    for (int c = t; c < CH3; c += 256) { float v = pooled[(size_t)g * CH3 + c]; row[c] = v; s += v; }
    #pragma unroll
    for (int o = 1; o < 64; o <<= 1) s += __shfl_xor(s, o);
    if (lane == 0) red[wv] = s;
    __syncthreads();
    float mu = (red[0] + red[1] + red[2] + red[3]) * (1.f / (float)CH3);
    float q = 0.f;
    for (int c = t; c < CH3; c += 256) { float d = row[c] - mu; q += d * d; }
    #pragma unroll
    for (int o = 1; o < 64; o <<= 1) q += __shfl_xor(q, o);
    if (lane == 0) red[4 + wv] = q;
    __syncthreads();
    float rstd = rsqrtf((red[4] + red[5] + red[6] + red[7]) * (1.f / (float)CH3) + 1e-5f);
    for (int c = t; c < CH3; c += 256)
        row[c] = (row[c] - mu) * rstd * olnw[c] + olnb[c];
    __syncthreads();
    int j = t & 31, slice = t >> 5;
    float a = 0.f;
    int cb = slice * (CH3 / 8);
    for (int c = cb; c < cb + CH3 / 8; ++c) a += row[c] * wout[(size_t)c * 32 + j];
    parts[slice][j] = a;
    __syncthreads();
    if (t < 32) {
        float r = bout[t];
        #pragma unroll
        for (int si = 0; si < 8; ++si) r += parts[si][t];
        outp[(size_t)g * 32 + t] = r;
    }
}

// ---------- launch ----------
extern "C" void kernel_launch(void* const* d_in, const int* in_sizes, int n_in,
                              void* d_out, int out_size, void* d_ws, size_t ws_size,
                              hipStream_t stream) {
    const float* x     = (const float*)d_in[0];
    const int*   ei    = (const int*)d_in[1];     // [2][E] int32
    const int*   batch = (const int*)d_in[2];
    const float* w_in  = (const float*)d_in[3];
    const float* b_in  = (const float*)d_in[4];
    const float* Wl    = (const float*)d_in[5];
    const float* bl    = (const float*)d_in[6];
    const float* Wr    = (const float*)d_in[7];
    const float* br    = (const float*)d_in[8];
    const float* att   = (const float*)d_in[9];
    const float* gbias = (const float*)d_in[10];
    const float* lnw   = (const float*)d_in[11];
    const float* lnb   = (const float*)d_in[12];
    const float* olnw  = (const float*)d_in[13];
    const float* olnb  = (const float*)d_in[14];
    const float* wout  = (const float*)d_in[15];
    const float* bout  = (const float*)d_in[16];

    char* ws = (char*)d_ws;
    size_t off = 0;
    auto alloc = [&](size_t bytes) -> void* {
        void* p = ws + off;
        off = (off + bytes + 255) & ~(size_t)255;
        return p;
    };
    ushort* h0     = (ushort*)alloc((size_t)N_NODES * CH * 2);
    ushort* hc     = (ushort*)alloc((size_t)N_NODES * CH3 * 2);
    ushort* xlbuf  = (ushort*)alloc((size_t)N_NODES * CH * 2);
    ushort* xrbuf  = (ushort*)alloc((size_t)N_NODES * CH * 2);
    ushort* wt_in  = (ushort*)alloc((size_t)CH * CH * 2);
    ushort* wt_l   = (ushort*)alloc((size_t)3 * 1536 * CH * 2);
    int*    deg    = (int*)alloc((size_t)N_NODES * 4);
    int*    rowptr = (int*)alloc((size_t)(N_NODES + 1) * 4);
    int*    cursor = (int*)alloc((size_t)N_NODES * 4);
    int*    csrc   = (int*)alloc((size_t)(N_EDGES + N_NODES) * 4);
    int*    gcount = (int*)alloc(256 * 4);
    int*    gstart = (int*)alloc(257 * 4);
    float*  pooled = (float*)alloc((size_t)NGRAPH * CH3 * 4);
    if (off > ws_size) return;

    // bf16 copy of x aliases hc (x is consumed by the h0-GEMM before hc's first write)
    ushort* xc = hc;

    // 1) convert x to bf16; all 7 weight transposes in one dispatch
    cvt_x_kernel<<<(N_NODES * CH / 4 + 255) / 256, 256, 0, stream>>>(x, xc, N_NODES * CH / 4);
    transpose_cvt_all<<<dim3(24, 24, 7), dim3(32, 8), 0, stream>>>(w_in, Wl, Wr, wt_in, wt_l);

    // 2) CSR by dst + graph segments
    int nb = (N_NODES + 255) / 256, eb = (N_EDGES + 255) / 256;
    hipMemsetAsync(deg, 0, (size_t)N_NODES * 4, stream);
    hipMemsetAsync(gcount, 0, 256 * 4, stream);
    count_both_kernel<<<eb, 256, 0, stream>>>(ei + N_EDGES, deg, N_EDGES, batch, gcount, N_NODES);
    scan_kernel<<<1, 1024, 0, stream>>>(deg, rowptr, N_NODES);
    selfloop_kernel<<<nb, 256, 0, stream>>>(rowptr, csrc, cursor, N_NODES);
    scatter_kernel<<<eb, 256, 0, stream>>>(ei, ei + N_EDGES, cursor, csrc, N_EDGES);
    gscan_kernel<<<1, 256, 0, stream>>>(gcount, gstart);

    // 3) h0 = x @ w_in + b_in (all cols -> Cx)
    gemm_bf16_kernel<<<dim3(157, 6), 256, 0, stream>>>(
        xc, CH, wt_in, b_in, b_in, CH, h0, CH, h0, CH, N_NODES);

    // 4) three GATv2 layers (GEMM splits xl/xr into dense per-projection tables)
    for (int l = 0; l < 3; ++l) {
        const ushort* hprev = (l == 0) ? h0 : (hc + (size_t)(l - 1) * CH);
        int ldh = (l == 0) ? CH : CH3;
        gemm_bf16_kernel<<<dim3(157, 12), 256, 0, stream>>>(
            hprev, ldh, wt_l + (size_t)l * 1536 * CH,
            bl + (size_t)l * CH, br + (size_t)l * CH, CH,
            xlbuf, CH, xrbuf, CH, N_NODES);
        gat_node_kernel<<<N_NODES / 2, 256, 0, stream>>>(
            xlbuf, xrbuf, hprev, ldh, rowptr, csrc,
            att + (size_t)l * CH, gbias + (size_t)l * CH,
            lnw + (size_t)l * CH, lnb + (size_t)l * CH,
            hc + (size_t)l * CH, N_NODES);
    }

    // 5) pool + head (all f32, f32 output)
    pool_kernel<<<dim3(NGRAPH, CH3 / 256), 256, 0, stream>>>(hc, gstart, pooled);
    head_kernel<<<NGRAPH, 256, 0, stream>>>(pooled, olnw, olnb, wout, bout, (float*)d_out);
}

// Round 11
// 774.931 us; speedup vs baseline: 1.0364x; 1.0364x over previous
//
#include <hip/hip_runtime.h>

#define N_NODES 20000
#define N_EDGES 160000
#define CH      768
#define CH3     2304
#define NGRAPH  256
#define NCLS    32

typedef __bf16 bf16v8 __attribute__((ext_vector_type(8)));
typedef float  f32x4  __attribute__((ext_vector_type(4)));

// ---------- helpers ----------
__device__ __forceinline__ float b2f(ushort u) {
    union { float f; unsigned u; } x; x.u = ((unsigned)u) << 16; return x.f;
}
__device__ __forceinline__ ushort f2b(float f) {
    union { float f; unsigned u; } x; x.f = f;
    unsigned r = x.u + 0x7FFFu + ((x.u >> 16) & 1u);
    return (ushort)(r >> 16);
}
__device__ __forceinline__ void load6(const ushort* __restrict__ p, float* o) {
    const ushort2* q = (const ushort2*)p;   // 4B-aligned (lane*12 B offsets)
    ushort2 a = q[0], b = q[1], c = q[2];
    o[0]=b2f(a.x); o[1]=b2f(a.y);
    o[2]=b2f(b.x); o[3]=b2f(b.y);
    o[4]=b2f(c.x); o[5]=b2f(c.y);
}
__device__ __forceinline__ void load6f(const float* __restrict__ p, float* o) {
    const float2* q = (const float2*)p;     // 8B-aligned (lane*24 B offsets)
    float2 a = q[0], b = q[1], c = q[2];
    o[0]=a.x; o[1]=a.y; o[2]=b.x; o[3]=b.y; o[4]=c.x; o[5]=c.y;
}
__device__ __forceinline__ void async_copy16(void* lds, const void* gp) {
    __builtin_amdgcn_global_load_lds((const void __attribute__((address_space(1)))*)gp,
                                     (void __attribute__((address_space(3)))*)lds, 16, 0, 0);
}

// ---------- f32 -> bf16 conversion (4-wide) ----------
__global__ void cvt_x_kernel(const float* __restrict__ src, ushort* __restrict__ dst, int n4) {
    int i = blockIdx.x * 256 + threadIdx.x;
    if (i >= n4) return;
    float4 v = ((const float4*)src)[i];
    ushort4 o; o.x = f2b(v.x); o.y = f2b(v.y); o.z = f2b(v.z); o.w = f2b(v.w);
    ((ushort4*)dst)[i] = o;
}

// ---------- all 7 weight transposes (+cvt) in one dispatch: grid (24,24,7) ----------
__global__ void transpose_cvt_all(const float* __restrict__ w_in,
                                  const float* __restrict__ Wl,
                                  const float* __restrict__ Wr,
                                  ushort* __restrict__ wt_in,
                                  ushort* __restrict__ wt_l) {
    __shared__ float tile[32][33];
    int z = blockIdx.z;
    const float* in;
    ushort* out;
    if (z == 0) { in = w_in; out = wt_in; }
    else {
        int l = (z - 1) >> 1, isr = (z - 1) & 1;
        in  = (isr ? Wr : Wl) + (size_t)l * CH * CH;
        out = wt_l + (size_t)l * 1536 * CH + (size_t)isr * CH * CH;
    }
    int bx = blockIdx.x * 32, by = blockIdx.y * 32;
    int tx = threadIdx.x, ty = threadIdx.y;
    #pragma unroll
    for (int i = ty; i < 32; i += 8) tile[i][tx] = in[(size_t)(by + i) * CH + bx + tx];
    __syncthreads();
    #pragma unroll
    for (int i = ty; i < 32; i += 8) out[(size_t)(bx + i) * CH + by + tx] = f2b(tile[tx][i]);
}

// ---------- CSR build ----------
__global__ void count_both_kernel(const int* __restrict__ dst, int* __restrict__ deg, int e,
                                  const int* __restrict__ batch, int* __restrict__ gcount, int n) {
    int i = blockIdx.x * 256 + threadIdx.x;
    if (i < e) atomicAdd(&deg[dst[i]], 1);
    if (i < n) { atomicAdd(&deg[i], 1); atomicAdd(&gcount[batch[i]], 1); }
}
__global__ __launch_bounds__(1024) void scan_kernel(const int* __restrict__ deg,
                                                    int* __restrict__ rowptr, int n) {
    __shared__ int part[1024];
    int t = threadIdx.x;
    const int chunk = (n + 1023) / 1024;
    int base = t * chunk;
    int s = 0;
    for (int i = 0; i < chunk; ++i) { int idx = base + i; if (idx < n) s += deg[idx]; }
    part[t] = s; __syncthreads();
    for (int off = 1; off < 1024; off <<= 1) {
        int v = (t >= off) ? part[t - off] : 0;
        __syncthreads();
        part[t] += v;
        __syncthreads();
    }
    int run = (t == 0) ? 0 : part[t - 1];
    for (int i = 0; i < chunk; ++i) {
        int idx = base + i;
        if (idx < n) { rowptr[idx] = run; run += deg[idx]; }
    }
    if (t == 1023) rowptr[n] = part[1023];
}
__global__ void selfloop_kernel(const int* __restrict__ rowptr, int* __restrict__ csrc,
                                int* __restrict__ cursor, int n) {
    int i = blockIdx.x * 256 + threadIdx.x;
    if (i < n) { int p = rowptr[i]; csrc[p] = i; cursor[i] = p + 1; }
}
__global__ void scatter_kernel(const int* __restrict__ src, const int* __restrict__ dst,
                               int* __restrict__ cursor, int* __restrict__ csrc, int e) {
    int i = blockIdx.x * 256 + threadIdx.x;
    if (i < e) { int p = atomicAdd(&cursor[dst[i]], 1); csrc[p] = src[i]; }
}
__global__ __launch_bounds__(256) void gscan_kernel(const int* __restrict__ gcount,
                                                    int* __restrict__ gstart) {
    __shared__ int p[256];
    int t = threadIdx.x;
    p[t] = gcount[t]; __syncthreads();
    for (int off = 1; off < 256; off <<= 1) {
        int v = (t >= off) ? p[t - off] : 0;
        __syncthreads();
        p[t] += v;
        __syncthreads();
    }
    gstart[t] = p[t] - gcount[t];
    if (t == 255) gstart[256] = p[255];
}

// ---------- GEMM: C[M,Ncols] = A[M,768] * Bt^T + bias(f32), bf16 in, fp32 accum ----------
// Panel swizzle (R6): FETCH 191->46MB. Single-C epilogue (R10's split-C regressed).
__global__ __launch_bounds__(256) void gemm_bf16_kernel(
    const ushort* __restrict__ A, int lda,
    const ushort* __restrict__ Bt,
    const float* __restrict__ biasA, const float* __restrict__ biasB, int nsplit,
    ushort* __restrict__ C, int ldc, int M) {
    __shared__ __bf16 As[128 * 32];
    __shared__ __bf16 Bs[128 * 32];
    int tid = threadIdx.x;
    int wave = tid >> 6, lane = tid & 63;
    int wr = wave >> 1, wc = wave & 1;

    int bid = blockIdx.y * gridDim.x + blockIdx.x;
    int pf = 8 * gridDim.y;
    int p  = bid / pf;
    int rem = bid - p * pf;
    int rp = min(8, (int)gridDim.x - p * 8);
    int row_t = p * 8 + rem % rp;
    int col_t = rem / rp;
    int row0 = row_t * 128, col0 = col_t * 128;

    int c1 = wave * 64 + lane, c2 = c1 + 256;
    int ar1 = min(row0 + (c1 >> 2), M - 1), ak1 = (c1 & 3) * 8;
    int ar2 = min(row0 + (c2 >> 2), M - 1), ak2 = (c2 & 3) * 8;
    int br1 = col0 + (c1 >> 2), br2 = col0 + (c2 >> 2);
    const ushort* a1 = A + (size_t)ar1 * lda + ak1;
    const ushort* a2 = A + (size_t)ar2 * lda + ak2;
    const ushort* b1 = Bt + (size_t)br1 * CH + ak1;
    const ushort* b2 = Bt + (size_t)br2 * CH + ak2;
    __bf16* asb1 = As + (wave * 64) * 8;
    __bf16* asb2 = As + (256 + wave * 64) * 8;
    __bf16* bsb1 = Bs + (wave * 64) * 8;
    __bf16* bsb2 = Bs + (256 + wave * 64) * 8;

    f32x4 acc[4][4] = {};
    int l16 = lane & 15, lq = lane >> 4;

    for (int k0 = 0; k0 < CH; k0 += 32) {
        async_copy16(asb1, a1 + k0);
        async_copy16(asb2, a2 + k0);
        async_copy16(bsb1, b1 + k0);
        async_copy16(bsb2, b2 + k0);
        __syncthreads();
        bf16v8 av[4], bv[4];
        #pragma unroll
        for (int i = 0; i < 4; ++i)
            av[i] = *(const bf16v8*)(As + ((wr * 64 + i * 16 + l16) * 32 + lq * 8));
        #pragma unroll
        for (int j = 0; j < 4; ++j)
            bv[j] = *(const bf16v8*)(Bs + ((wc * 64 + j * 16 + l16) * 32 + lq * 8));
        #pragma unroll
        for (int i = 0; i < 4; ++i)
            #pragma unroll
            for (int j = 0; j < 4; ++j)
                acc[i][j] = __builtin_amdgcn_mfma_f32_16x16x32_bf16(av[i], bv[j], acc[i][j], 0, 0, 0);
        __syncthreads();
    }
    #pragma unroll
    for (int i = 0; i < 4; ++i) {
        int mbase = row0 + wr * 64 + i * 16 + lq * 4;
        #pragma unroll
        for (int j = 0; j < 4; ++j) {
            int col = col0 + wc * 64 + j * 16 + l16;
            float bb = (col < nsplit) ? biasA[col] : biasB[col - nsplit];
            #pragma unroll
            for (int r = 0; r < 4; ++r) {
                int mm = mbase + r;
                if (mm < M) C[(size_t)mm * ldc + col] = f2b(acc[i][j][r] + bb);
            }
        }
    }
}

// ---------- fused GATv2 node kernel. Two waves per node (6 ch/lane halves).
// QUAD independent online-softmax chains (edges e, e+1, e+2, e+3 in flight)
// merged exactly at the end -> 4 gather streams per wave for latency hiding.
__global__ __launch_bounds__(256) void gat_node_kernel(
    const ushort* __restrict__ xlxr,          // [N][1536] bf16: xl | xr
    const ushort* __restrict__ hin, int ldh,  // residual rows (bf16)
    const int* __restrict__ rowptr, const int* __restrict__ csrc,
    const float* __restrict__ att, const float* __restrict__ gbias,
    const float* __restrict__ lnw, const float* __restrict__ lnb,
    ushort* __restrict__ hout, int nn) {
    __shared__ float sred[2][2][2];   // [node-slot][metric][half]
    int wv = threadIdx.x >> 6, lane = threadIdx.x & 63;
    int slot = wv >> 1, half = wv & 1;
    int n = blockIdx.x * 2 + slot;    // grid exactly nn/2
    int c0 = half * 384 + lane * 6;
    const ushort* __restrict__ xbase = xlxr + c0;
    float attv[6], xr[6];
    load6f(att + c0, attv);
    load6(xbase + (size_t)n * 1536 + CH, xr);
    float m0 = -1e30f, m1 = -1e30f, m2 = -1e30f, m3 = -1e30f;
    float s0 = 0.f, s1 = 0.f, s2 = 0.f, s3 = 0.f;
    float a0[6] = {}, a1[6] = {}, a2[6] = {}, a3[6] = {};
    int rs = rowptr[n], re = rowptr[n + 1];

    auto logit = [&](const float* xv) -> float {
        float d = 0.f;
        #pragma unroll
        for (int j = 0; j < 6; ++j) {
            float v = xv[j] + xr[j];
            v = (v > 0.f) ? v : 0.2f * v;
            d = fmaf(v, attv[j], d);
        }
        d += __shfl_xor(d, 1);
        d += __shfl_xor(d, 2);
        d += __shfl_xor(d, 4);
        d += __shfl_xor(d, 8);   // 16-lane head logit
        return d;
    };
    auto upd = [&](float& m, float& s, float (&ac)[6], const float* xv) {
        float d = logit(xv);
        float nm = fmaxf(m, d);
        float sc = __expf(m - nm), ex = __expf(d - nm);
        s = s * sc + ex;
        #pragma unroll
        for (int j = 0; j < 6; ++j) ac[j] = fmaf(ac[j], sc, ex * xv[j]);
        m = nm;
    };

    int e = rs;
    for (; e + 3 < re; e += 4) {
        int i0 = csrc[e], i1 = csrc[e + 1], i2 = csrc[e + 2], i3 = csrc[e + 3];
        float xA[6], xB[6], xC[6], xD[6];
        load6(xbase + (size_t)i0 * 1536, xA);
        load6(xbase + (size_t)i1 * 1536, xB);
        load6(xbase + (size_t)i2 * 1536, xC);
        load6(xbase + (size_t)i3 * 1536, xD);
        upd(m0, s0, a0, xA);
        upd(m1, s1, a1, xB);
        upd(m2, s2, a2, xC);
        upd(m3, s3, a3, xD);
    }
    if (e < re) { float xA[6]; load6(xbase + (size_t)csrc[e] * 1536, xA); upd(m0, s0, a0, xA); ++e; }
    if (e < re) { float xB[6]; load6(xbase + (size_t)csrc[e] * 1536, xB); upd(m1, s1, a1, xB); ++e; }
    if (e < re) { float xC[6]; load6(xbase + (size_t)csrc[e] * 1536, xC); upd(m2, s2, a2, xC); ++e; }

    // merge the four chains (empty chains: exp(-1e30 - M) underflows to 0)
    float M = fmaxf(fmaxf(m0, m1), fmaxf(m2, m3));
    float w0 = __expf(m0 - M), w1 = __expf(m1 - M);
    float w2 = __expf(m2 - M), w3 = __expf(m3 - M);
    float inv = 1.f / (s0 * w0 + s1 * w1 + s2 * w2 + s3 * w3);
    float hres[6], gb[6], tv[6];
    load6(hin + (size_t)n * ldh + c0, hres);
    load6f(gbias + c0, gb);
    float lsum = 0.f, lsq = 0.f;
    #pragma unroll
    for (int j = 0; j < 6; ++j) {
        tv[j] = (a0[j] * w0 + a1[j] * w1 + a2[j] * w2 + a3[j] * w3) * inv + gb[j] + hres[j];
        lsum += tv[j];
        lsq = fmaf(tv[j], tv[j], lsq);
    }
    #pragma unroll
    for (int o = 1; o < 64; o <<= 1) { lsum += __shfl_xor(lsum, o); lsq += __shfl_xor(lsq, o); }
    if (lane == 0) { sred[slot][0][half] = lsum; sred[slot][1][half] = lsq; }
    __syncthreads();
    float S = sred[slot][0][0] + sred[slot][0][1];
    float Q = sred[slot][1][0] + sred[slot][1][1];
    float mu = S * (1.f / 768.f);
    float var = Q * (1.f / 768.f) - mu * mu;
    float rstd = rsqrtf(var + 1e-5f);
    float wv6[6], bv6[6];
    load6f(lnw + c0, wv6);
    load6f(lnb + c0, bv6);
    float g[6];
    #pragma unroll
    for (int j = 0; j < 6; ++j) {
        float y = (tv[j] - mu) * rstd * wv6[j] + bv6[j];
        g[j] = 0.5f * y * (1.f + erff(y * 0.70710678118f));
    }
    ushort2* o2 = (ushort2*)(hout + (size_t)n * CH3 + c0);
    ushort2 u0, u1, u2;
    u0.x = f2b(g[0]); u0.y = f2b(g[1]);
    u1.x = f2b(g[2]); u1.y = f2b(g[3]);
    u2.x = f2b(g[4]); u2.y = f2b(g[5]);
    o2[0] = u0; o2[1] = u1; o2[2] = u2;
}

// ---------- global mean pool: 4 independent accumulators ----------
__global__ __launch_bounds__(256) void pool_kernel(const ushort* __restrict__ hc,
                                                   const int* __restrict__ gstart,
                                                   float* __restrict__ pooled) {
    int g = blockIdx.x;
    int c = blockIdx.y * 256 + threadIdx.x;
    int s = gstart[g], e = gstart[g + 1];
    const ushort* p = hc + (size_t)s * CH3 + c;
    float a0 = 0.f, a1 = 0.f, a2 = 0.f, a3 = 0.f;
    int n = s;
    for (; n + 3 < e; n += 4) {
        a0 += b2f(p[0]);
        a1 += b2f(p[CH3]);
        a2 += b2f(p[2 * CH3]);
        a3 += b2f(p[3 * CH3]);
        p += 4 * CH3;
    }
    for (; n < e; ++n) { a0 += b2f(*p); p += CH3; }
    float a = (a0 + a1) + (a2 + a3);
    pooled[(size_t)g * CH3 + c] = a * (1.f / (float)max(e - s, 1));
}

// ---------- final LN + [2304x32] matmul (all f32) ----------
__global__ __launch_bounds__(256) void head_kernel(const float* __restrict__ pooled,
                                                   const float* __restrict__ olnw,
                                                   const float* __restrict__ olnb,
                                                   const float* __restrict__ wout,
                                                   const float* __restrict__ bout,
                                                   float* __restrict__ outp) {
    __shared__ float row[CH3];
    __shared__ float red[8];
    __shared__ float parts[8][32];
    int g = blockIdx.x, t = threadIdx.x;
    int lane = t & 63, wv = t >> 6;
    float s = 0.f;
    for (int c = t; c < CH3; c += 256) { float v = pooled[(size_t)g * CH3 + c]; row[c] = v; s += v; }
    #pragma unroll
    for (int o = 1; o < 64; o <<= 1) s += __shfl_xor(s, o);
    if (lane == 0) red[wv] = s;
    __syncthreads();
    float mu = (red[0] + red[1] + red[2] + red[3]) * (1.f / (float)CH3);
    float q = 0.f;
    for (int c = t; c < CH3; c += 256) { float d = row[c] - mu; q += d * d; }
    #pragma unroll
    for (int o = 1; o < 64; o <<= 1) q += __shfl_xor(q, o);
    if (lane == 0) red[4 + wv] = q;
    __syncthreads();
    float rstd = rsqrtf((red[4] + red[5] + red[6] + red[7]) * (1.f / (float)CH3) + 1e-5f);
    for (int c = t; c < CH3; c += 256)
        row[c] = (row[c] - mu) * rstd * olnw[c] + olnb[c];
    __syncthreads();
    int j = t & 31, slice = t >> 5;
    float a = 0.f;
    int cb = slice * (CH3 / 8);
    for (int c = cb; c < cb + CH3 / 8; ++c) a += row[c] * wout[(size_t)c * 32 + j];
    parts[slice][j] = a;
    __syncthreads();
    if (t < 32) {
        float r = bout[t];
        #pragma unroll
        for (int si = 0; si < 8; ++si) r += parts[si][t];
        outp[(size_t)g * 32 + t] = r;
    }
}

// ---------- launch ----------
extern "C" void kernel_launch(void* const* d_in, const int* in_sizes, int n_in,
                              void* d_out, int out_size, void* d_ws, size_t ws_size,
                              hipStream_t stream) {
    const float* x     = (const float*)d_in[0];
    const int*   ei    = (const int*)d_in[1];     // [2][E] int32
    const int*   batch = (const int*)d_in[2];
    const float* w_in  = (const float*)d_in[3];
    const float* b_in  = (const float*)d_in[4];
    const float* Wl    = (const float*)d_in[5];
    const float* bl    = (const float*)d_in[6];
    const float* Wr    = (const float*)d_in[7];
    const float* br    = (const float*)d_in[8];
    const float* att   = (const float*)d_in[9];
    const float* gbias = (const float*)d_in[10];
    const float* lnw   = (const float*)d_in[11];
    const float* lnb   = (const float*)d_in[12];
    const float* olnw  = (const float*)d_in[13];
    const float* olnb  = (const float*)d_in[14];
    const float* wout  = (const float*)d_in[15];
    const float* bout  = (const float*)d_in[16];

    char* ws = (char*)d_ws;
    size_t off = 0;
    auto alloc = [&](size_t bytes) -> void* {
        void* p = ws + off;
        off = (off + bytes + 255) & ~(size_t)255;
        return p;
    };
    ushort* h0     = (ushort*)alloc((size_t)N_NODES * CH * 2);
    ushort* hc     = (ushort*)alloc((size_t)N_NODES * CH3 * 2);
    ushort* xlxr   = (ushort*)alloc((size_t)N_NODES * 1536 * 2);
    ushort* wt_in  = (ushort*)alloc((size_t)CH * CH * 2);
    ushort* wt_l   = (ushort*)alloc((size_t)3 * 1536 * CH * 2);
    int*    deg    = (int*)alloc((size_t)N_NODES * 4);
    int*    rowptr = (int*)alloc((size_t)(N_NODES + 1) * 4);
    int*    cursor = (int*)alloc((size_t)N_NODES * 4);
    int*    csrc   = (int*)alloc((size_t)(N_EDGES + N_NODES) * 4);
    int*    gcount = (int*)alloc(256 * 4);
    int*    gstart = (int*)alloc(257 * 4);
    float*  pooled = (float*)alloc((size_t)NGRAPH * CH3 * 4);
    if (off > ws_size) return;

    // bf16 copy of x aliases hc (x is consumed by the h0-GEMM before hc's first write)
    ushort* xc = hc;

    // 1) convert x to bf16; all 7 weight transposes in one dispatch
    cvt_x_kernel<<<(N_NODES * CH / 4 + 255) / 256, 256, 0, stream>>>(x, xc, N_NODES * CH / 4);
    transpose_cvt_all<<<dim3(24, 24, 7), dim3(32, 8), 0, stream>>>(w_in, Wl, Wr, wt_in, wt_l);

    // 2) CSR by dst + graph segments
    int nb = (N_NODES + 255) / 256, eb = (N_EDGES + 255) / 256;
    hipMemsetAsync(deg, 0, (size_t)N_NODES * 4, stream);
    hipMemsetAsync(gcount, 0, 256 * 4, stream);
    count_both_kernel<<<eb, 256, 0, stream>>>(ei + N_EDGES, deg, N_EDGES, batch, gcount, N_NODES);
    scan_kernel<<<1, 1024, 0, stream>>>(deg, rowptr, N_NODES);
    selfloop_kernel<<<nb, 256, 0, stream>>>(rowptr, csrc, cursor, N_NODES);
    scatter_kernel<<<eb, 256, 0, stream>>>(ei, ei + N_EDGES, cursor, csrc, N_EDGES);
    gscan_kernel<<<1, 256, 0, stream>>>(gcount, gstart);

    // 3) h0 = x @ w_in + b_in
    gemm_bf16_kernel<<<dim3(157, 6), 256, 0, stream>>>(
        xc, CH, wt_in, b_in, b_in, CH, h0, CH, N_NODES);

    // 4) three GATv2 layers
    for (int l = 0; l < 3; ++l) {
        const ushort* hprev = (l == 0) ? h0 : (hc + (size_t)(l - 1) * CH);
        int ldh = (l == 0) ? CH : CH3;
        gemm_bf16_kernel<<<dim3(157, 12), 256, 0, stream>>>(
            hprev, ldh, wt_l + (size_t)l * 1536 * CH,
            bl + (size_t)l * CH, br + (size_t)l * CH, CH,
            xlxr, 1536, N_NODES);
        gat_node_kernel<<<N_NODES / 2, 256, 0, stream>>>(
            xlxr, hprev, ldh, rowptr, csrc,
            att + (size_t)l * CH, gbias + (size_t)l * CH,
            lnw + (size_t)l * CH, lnb + (size_t)l * CH,
            hc + (size_t)l * CH, N_NODES);
    }

    // 5) pool + head (all f32, f32 output)
    pool_kernel<<<dim3(NGRAPH, CH3 / 256), 256, 0, stream>>>(hc, gstart, pooled);
    head_kernel<<<NGRAPH, 256, 0, stream>>>(pooled, olnw, olnb, wout, bout, (float*)d_out);
}

// Round 12
// 712.390 us; speedup vs baseline: 1.1274x; 1.0878x over previous
//
#include <hip/hip_runtime.h>

#define N_NODES 20000
#define N_EDGES 160000
#define CH      768
#define CH3     2304
#define NGRAPH  256
#define NCLS    32

typedef __bf16 bf16v8 __attribute__((ext_vector_type(8)));
typedef float  f32x4  __attribute__((ext_vector_type(4)));

// ---------- helpers ----------
__device__ __forceinline__ float b2f(ushort u) {
    union { float f; unsigned u; } x; x.u = ((unsigned)u) << 16; return x.f;
}
__device__ __forceinline__ ushort f2b(float f) {
    union { float f; unsigned u; } x; x.f = f;
    unsigned r = x.u + 0x7FFFu + ((x.u >> 16) & 1u);
    return (ushort)(r >> 16);
}
__device__ __forceinline__ void load12(const ushort* __restrict__ p, float* o) {
    const ushort4* q = (const ushort4*)p;   // lane*12 ushorts = 24B -> 8B aligned
    ushort4 a = q[0], b = q[1], c = q[2];
    o[0]=b2f(a.x); o[1]=b2f(a.y); o[2]=b2f(a.z); o[3]=b2f(a.w);
    o[4]=b2f(b.x); o[5]=b2f(b.y); o[6]=b2f(b.z); o[7]=b2f(b.w);
    o[8]=b2f(c.x); o[9]=b2f(c.y); o[10]=b2f(c.z); o[11]=b2f(c.w);
}
__device__ __forceinline__ void load12f(const float* __restrict__ p, float* o) {
    const float4* q = (const float4*)p;     // lane*12 floats = 48B -> 16B aligned
    float4 a = q[0], b = q[1], c = q[2];
    o[0]=a.x; o[1]=a.y; o[2]=a.z; o[3]=a.w;
    o[4]=b.x; o[5]=b.y; o[6]=b.z; o[7]=b.w;
    o[8]=c.x; o[9]=c.y; o[10]=c.z; o[11]=c.w;
}
__device__ __forceinline__ void async_copy16(void* lds, const void* gp) {
    __builtin_amdgcn_global_load_lds((const void __attribute__((address_space(1)))*)gp,
                                     (void __attribute__((address_space(3)))*)lds, 16, 0, 0);
}

// ---------- f32 -> bf16 conversion (4-wide) ----------
__global__ void cvt_x_kernel(const float* __restrict__ src, ushort* __restrict__ dst, int n4) {
    int i = blockIdx.x * 256 + threadIdx.x;
    if (i >= n4) return;
    float4 v = ((const float4*)src)[i];
    ushort4 o; o.x = f2b(v.x); o.y = f2b(v.y); o.z = f2b(v.z); o.w = f2b(v.w);
    ((ushort4*)dst)[i] = o;
}

// ---------- all 7 weight transposes (+cvt) in one dispatch: grid (24,24,7) ----------
__global__ void transpose_cvt_all(const float* __restrict__ w_in,
                                  const float* __restrict__ Wl,
                                  const float* __restrict__ Wr,
                                  ushort* __restrict__ wt_in,
                                  ushort* __restrict__ wt_l) {
    __shared__ float tile[32][33];
    int z = blockIdx.z;
    const float* in;
    ushort* out;
    if (z == 0) { in = w_in; out = wt_in; }
    else {
        int l = (z - 1) >> 1, isr = (z - 1) & 1;
        in  = (isr ? Wr : Wl) + (size_t)l * CH * CH;
        out = wt_l + (size_t)l * 1536 * CH + (size_t)isr * CH * CH;
    }
    int bx = blockIdx.x * 32, by = blockIdx.y * 32;
    int tx = threadIdx.x, ty = threadIdx.y;
    #pragma unroll
    for (int i = ty; i < 32; i += 8) tile[i][tx] = in[(size_t)(by + i) * CH + bx + tx];
    __syncthreads();
    #pragma unroll
    for (int i = ty; i < 32; i += 8) out[(size_t)(bx + i) * CH + by + tx] = f2b(tile[tx][i]);
}

// ---------- CSR build ----------
__global__ void count_both_kernel(const int* __restrict__ dst, int* __restrict__ deg, int e,
                                  const int* __restrict__ batch, int* __restrict__ gcount, int n) {
    int i = blockIdx.x * 256 + threadIdx.x;
    if (i < e) atomicAdd(&deg[dst[i]], 1);
    if (i < n) { atomicAdd(&deg[i], 1); atomicAdd(&gcount[batch[i]], 1); }
}
__global__ __launch_bounds__(1024) void scan_kernel(const int* __restrict__ deg,
                                                    int* __restrict__ rowptr, int n) {
    __shared__ int part[1024];
    int t = threadIdx.x;
    const int chunk = (n + 1023) / 1024;
    int base = t * chunk;
    int s = 0;
    for (int i = 0; i < chunk; ++i) { int idx = base + i; if (idx < n) s += deg[idx]; }
    part[t] = s; __syncthreads();
    for (int off = 1; off < 1024; off <<= 1) {
        int v = (t >= off) ? part[t - off] : 0;
        __syncthreads();
        part[t] += v;
        __syncthreads();
    }
    int run = (t == 0) ? 0 : part[t - 1];
    for (int i = 0; i < chunk; ++i) {
        int idx = base + i;
        if (idx < n) { rowptr[idx] = run; run += deg[idx]; }
    }
    if (t == 1023) rowptr[n] = part[1023];
}
__global__ void selfloop_kernel(const int* __restrict__ rowptr, int* __restrict__ csrc,
                                int* __restrict__ cursor, int n) {
    int i = blockIdx.x * 256 + threadIdx.x;
    if (i < n) { int p = rowptr[i]; csrc[p] = i; cursor[i] = p + 1; }
}
__global__ void scatter_kernel(const int* __restrict__ src, const int* __restrict__ dst,
                               int* __restrict__ cursor, int* __restrict__ csrc, int e) {
    int i = blockIdx.x * 256 + threadIdx.x;
    if (i < e) { int p = atomicAdd(&cursor[dst[i]], 1); csrc[p] = src[i]; }
}
__global__ __launch_bounds__(256) void gscan_kernel(const int* __restrict__ gcount,
                                                    int* __restrict__ gstart) {
    __shared__ int p[256];
    int t = threadIdx.x;
    p[t] = gcount[t]; __syncthreads();
    for (int off = 1; off < 256; off <<= 1) {
        int v = (t >= off) ? p[t - off] : 0;
        __syncthreads();
        p[t] += v;
        __syncthreads();
    }
    gstart[t] = p[t] - gcount[t];
    if (t == 255) gstart[256] = p[255];
}

// ---------- GEMM: C[M,Ncols] = A[M,768] * Bt^T + bias(f32), bf16 in, fp32 accum ----------
__global__ __launch_bounds__(256) void gemm_bf16_kernel(
    const ushort* __restrict__ A, int lda,
    const ushort* __restrict__ Bt,
    const float* __restrict__ biasA, const float* __restrict__ biasB, int nsplit,
    ushort* __restrict__ C, int ldc, int M) {
    __shared__ __bf16 As[128 * 32];
    __shared__ __bf16 Bs[128 * 32];
    int tid = threadIdx.x;
    int wave = tid >> 6, lane = tid & 63;
    int wr = wave >> 1, wc = wave & 1;

    int bid = blockIdx.y * gridDim.x + blockIdx.x;
    int pf = 8 * gridDim.y;
    int p  = bid / pf;
    int rem = bid - p * pf;
    int rp = min(8, (int)gridDim.x - p * 8);
    int row_t = p * 8 + rem % rp;
    int col_t = rem / rp;
    int row0 = row_t * 128, col0 = col_t * 128;

    int c1 = wave * 64 + lane, c2 = c1 + 256;
    int ar1 = min(row0 + (c1 >> 2), M - 1), ak1 = (c1 & 3) * 8;
    int ar2 = min(row0 + (c2 >> 2), M - 1), ak2 = (c2 & 3) * 8;
    int br1 = col0 + (c1 >> 2), br2 = col0 + (c2 >> 2);
    const ushort* a1 = A + (size_t)ar1 * lda + ak1;
    const ushort* a2 = A + (size_t)ar2 * lda + ak2;
    const ushort* b1 = Bt + (size_t)br1 * CH + ak1;
    const ushort* b2 = Bt + (size_t)br2 * CH + ak2;
    __bf16* asb1 = As + (wave * 64) * 8;
    __bf16* asb2 = As + (256 + wave * 64) * 8;
    __bf16* bsb1 = Bs + (wave * 64) * 8;
    __bf16* bsb2 = Bs + (256 + wave * 64) * 8;

    f32x4 acc[4][4] = {};
    int l16 = lane & 15, lq = lane >> 4;

    for (int k0 = 0; k0 < CH; k0 += 32) {
        async_copy16(asb1, a1 + k0);
        async_copy16(asb2, a2 + k0);
        async_copy16(bsb1, b1 + k0);
        async_copy16(bsb2, b2 + k0);
        __syncthreads();
        bf16v8 av[4], bv[4];
        #pragma unroll
        for (int i = 0; i < 4; ++i)
            av[i] = *(const bf16v8*)(As + ((wr * 64 + i * 16 + l16) * 32 + lq * 8));
        #pragma unroll
        for (int j = 0; j < 4; ++j)
            bv[j] = *(const bf16v8*)(Bs + ((wc * 64 + j * 16 + l16) * 32 + lq * 8));
        #pragma unroll
        for (int i = 0; i < 4; ++i)
            #pragma unroll
            for (int j = 0; j < 4; ++j)
                acc[i][j] = __builtin_amdgcn_mfma_f32_16x16x32_bf16(av[i], bv[j], acc[i][j], 0, 0, 0);
        __syncthreads();
    }
    #pragma unroll
    for (int i = 0; i < 4; ++i) {
        int mbase = row0 + wr * 64 + i * 16 + lq * 4;
        #pragma unroll
        for (int j = 0; j < 4; ++j) {
            int col = col0 + wc * 64 + j * 16 + l16;
            float bb = (col < nsplit) ? biasA[col] : biasB[col - nsplit];
            #pragma unroll
            for (int r = 0; r < 4; ++r) {
                int mm = mbase + r;
                if (mm < M) C[(size_t)mm * ldc + col] = f2b(acc[i][j][r] + bb);
            }
        }
    }
}

// ---------- fused GATv2 node kernel. ONE wave per node (12 ch/lane), NO-MAX
// softmax (logits are LN-bounded, |logit| <~ 8 -> exp safe un-shifted; softmax
// is shift-invariant so result is identical up to rounding). Loop-carried work
// is pure fma accumulation; dual chains kept only for load-level parallelism.
// R11 evidence: VALUBusy 85% -> this cut targets instructions, not latency.
__global__ __launch_bounds__(256) void gat_node_kernel(
    const ushort* __restrict__ xlxr,          // [N][1536] bf16: xl | xr
    const ushort* __restrict__ hin, int ldh,  // residual rows (bf16)
    const int* __restrict__ rowptr, const int* __restrict__ csrc,
    const float* __restrict__ att, const float* __restrict__ gbias,
    const float* __restrict__ lnw, const float* __restrict__ lnb,
    ushort* __restrict__ hout, int nn) {
    int wv = threadIdx.x >> 6, lane = threadIdx.x & 63;
    int n = blockIdx.x * 4 + wv;     // grid exactly nn/4
    int c0 = lane * 12;
    const ushort* __restrict__ xbase = xlxr + c0;
    float attv[12], xr[12], acc1[12] = {}, acc2[12] = {};
    load12f(att + c0, attv);
    load12(xbase + (size_t)n * 1536 + CH, xr);
    float s1 = 0.f, s2 = 0.f;
    int rs = rowptr[n], re = rowptr[n + 1];
    int e = rs;
    for (; e + 1 < re; e += 2) {
        int sa = csrc[e], sb = csrc[e + 1];
        float xa[12], xb[12];
        load12(xbase + (size_t)sa * 1536, xa);
        load12(xbase + (size_t)sb * 1536, xb);
        float da = 0.f, db = 0.f;
        #pragma unroll
        for (int j = 0; j < 12; ++j) {
            float va = xa[j] + xr[j]; va = fmaxf(va, 0.2f * va);
            float vb = xb[j] + xr[j]; vb = fmaxf(vb, 0.2f * vb);
            da = fmaf(va, attv[j], da);
            db = fmaf(vb, attv[j], db);
        }
        da += __shfl_xor(da, 1); db += __shfl_xor(db, 1);
        da += __shfl_xor(da, 2); db += __shfl_xor(db, 2);
        da += __shfl_xor(da, 4); db += __shfl_xor(db, 4);   // 8-lane head logits
        float ea = __expf(da), eb = __expf(db);
        s1 += ea; s2 += eb;
        #pragma unroll
        for (int j = 0; j < 12; ++j) {
            acc1[j] = fmaf(ea, xa[j], acc1[j]);
            acc2[j] = fmaf(eb, xb[j], acc2[j]);
        }
    }
    if (e < re) {   // odd tail -> chain 1
        int sa = csrc[e];
        float xa[12];
        load12(xbase + (size_t)sa * 1536, xa);
        float da = 0.f;
        #pragma unroll
        for (int j = 0; j < 12; ++j) {
            float va = xa[j] + xr[j]; va = fmaxf(va, 0.2f * va);
            da = fmaf(va, attv[j], da);
        }
        da += __shfl_xor(da, 1);
        da += __shfl_xor(da, 2);
        da += __shfl_xor(da, 4);
        float ea = __expf(da);
        s1 += ea;
        #pragma unroll
        for (int j = 0; j < 12; ++j) acc1[j] = fmaf(ea, xa[j], acc1[j]);
    }
    float inv = 1.f / (s1 + s2);
    float hres[12], gb[12], tv[12];
    load12(hin + (size_t)n * ldh + c0, hres);
    load12f(gbias + c0, gb);
    float lsum = 0.f, lsq = 0.f;
    #pragma unroll
    for (int j = 0; j < 12; ++j) {
        tv[j] = (acc1[j] + acc2[j]) * inv + gb[j] + hres[j];
        lsum += tv[j];
        lsq = fmaf(tv[j], tv[j], lsq);
    }
    #pragma unroll
    for (int o = 1; o < 64; o <<= 1) { lsum += __shfl_xor(lsum, o); lsq += __shfl_xor(lsq, o); }
    float mu = lsum * (1.f / 768.f);
    float var = lsq * (1.f / 768.f) - mu * mu;
    float rstd = rsqrtf(var + 1e-5f);
    float wv12[12], bv12[12];
    load12f(lnw + c0, wv12);
    load12f(lnb + c0, bv12);
    ushort* op = hout + (size_t)n * CH3 + c0;
    ushort4 u[3];
    #pragma unroll
    for (int k = 0; k < 3; ++k) {
        float g[4];
        #pragma unroll
        for (int q = 0; q < 4; ++q) {
            int j = k * 4 + q;
            float y = (tv[j] - mu) * rstd * wv12[j] + bv12[j];
            g[q] = 0.5f * y * (1.f + erff(y * 0.70710678118f));
        }
        u[k].x = f2b(g[0]); u[k].y = f2b(g[1]); u[k].z = f2b(g[2]); u[k].w = f2b(g[3]);
        ((ushort4*)op)[k] = u[k];
    }
}

// ---------- global mean pool: 4 independent accumulators ----------
__global__ __launch_bounds__(256) void pool_kernel(const ushort* __restrict__ hc,
                                                   const int* __restrict__ gstart,
                                                   float* __restrict__ pooled) {
    int g = blockIdx.x;
    int c = blockIdx.y * 256 + threadIdx.x;
    int s = gstart[g], e = gstart[g + 1];
    const ushort* p = hc + (size_t)s * CH3 + c;
    float a0 = 0.f, a1 = 0.f, a2 = 0.f, a3 = 0.f;
    int n = s;
    for (; n + 3 < e; n += 4) {
        a0 += b2f(p[0]);
        a1 += b2f(p[CH3]);
        a2 += b2f(p[2 * CH3]);
        a3 += b2f(p[3 * CH3]);
        p += 4 * CH3;
    }
    for (; n < e; ++n) { a0 += b2f(*p); p += CH3; }
    float a = (a0 + a1) + (a2 + a3);
    pooled[(size_t)g * CH3 + c] = a * (1.f / (float)max(e - s, 1));
}

// ---------- final LN + [2304x32] matmul (all f32) ----------
__global__ __launch_bounds__(256) void head_kernel(const float* __restrict__ pooled,
                                                   const float* __restrict__ olnw,
                                                   const float* __restrict__ olnb,
                                                   const float* __restrict__ wout,
                                                   const float* __restrict__ bout,
                                                   float* __restrict__ outp) {
    __shared__ float row[CH3];
    __shared__ float red[8];
    __shared__ float parts[8][32];
    int g = blockIdx.x, t = threadIdx.x;
    int lane = t & 63, wv = t >> 6;
    float s = 0.f;
    for (int c = t; c < CH3; c += 256) { float v = pooled[(size_t)g * CH3 + c]; row[c] = v; s += v; }
    #pragma unroll
    for (int o = 1; o < 64; o <<= 1) s += __shfl_xor(s, o);
    if (lane == 0) red[wv] = s;
    __syncthreads();
    float mu = (red[0] + red[1] + red[2] + red[3]) * (1.f / (float)CH3);
    float q = 0.f;
    for (int c = t; c < CH3; c += 256) { float d = row[c] - mu; q += d * d; }
    #pragma unroll
    for (int o = 1; o < 64; o <<= 1) q += __shfl_xor(q, o);
    if (lane == 0) red[4 + wv] = q;
    __syncthreads();
    float rstd = rsqrtf((red[4] + red[5] + red[6] + red[7]) * (1.f / (float)CH3) + 1e-5f);
    for (int c = t; c < CH3; c += 256)
        row[c] = (row[c] - mu) * rstd * olnw[c] + olnb[c];
    __syncthreads();
    int j = t & 31, slice = t >> 5;
    float a = 0.f;
    int cb = slice * (CH3 / 8);
    for (int c = cb; c < cb + CH3 / 8; ++c) a += row[c] * wout[(size_t)c * 32 + j];
    parts[slice][j] = a;
    __syncthreads();
    if (t < 32) {
        float r = bout[t];
        #pragma unroll
        for (int si = 0; si < 8; ++si) r += parts[si][t];
        outp[(size_t)g * 32 + t] = r;
    }
}

// ---------- launch ----------
extern "C" void kernel_launch(void* const* d_in, const int* in_sizes, int n_in,
                              void* d_out, int out_size, void* d_ws, size_t ws_size,
                              hipStream_t stream) {
    const float* x     = (const float*)d_in[0];
    const int*   ei    = (const int*)d_in[1];     // [2][E] int32
    const int*   batch = (const int*)d_in[2];
    const float* w_in  = (const float*)d_in[3];
    const float* b_in  = (const float*)d_in[4];
    const float* Wl    = (const float*)d_in[5];
    const float* bl    = (const float*)d_in[6];
    const float* Wr    = (const float*)d_in[7];
    const float* br    = (const float*)d_in[8];
    const float* att   = (const float*)d_in[9];
    const float* gbias = (const float*)d_in[10];
    const float* lnw   = (const float*)d_in[11];
    const float* lnb   = (const float*)d_in[12];
    const float* olnw  = (const float*)d_in[13];
    const float* olnb  = (const float*)d_in[14];
    const float* wout  = (const float*)d_in[15];
    const float* bout  = (const float*)d_in[16];

    char* ws = (char*)d_ws;
    size_t off = 0;
    auto alloc = [&](size_t bytes) -> void* {
        void* p = ws + off;
        off = (off + bytes + 255) & ~(size_t)255;
        return p;
    };
    ushort* h0     = (ushort*)alloc((size_t)N_NODES * CH * 2);
    ushort* hc     = (ushort*)alloc((size_t)N_NODES * CH3 * 2);
    ushort* xlxr   = (ushort*)alloc((size_t)N_NODES * 1536 * 2);
    ushort* wt_in  = (ushort*)alloc((size_t)CH * CH * 2);
    ushort* wt_l   = (ushort*)alloc((size_t)3 * 1536 * CH * 2);
    int*    deg    = (int*)alloc((size_t)N_NODES * 4);
    int*    rowptr = (int*)alloc((size_t)(N_NODES + 1) * 4);
    int*    cursor = (int*)alloc((size_t)N_NODES * 4);
    int*    csrc   = (int*)alloc((size_t)(N_EDGES + N_NODES) * 4);
    int*    gcount = (int*)alloc(256 * 4);
    int*    gstart = (int*)alloc(257 * 4);
    float*  pooled = (float*)alloc((size_t)NGRAPH * CH3 * 4);
    if (off > ws_size) return;

    // bf16 copy of x aliases hc (x is consumed by the h0-GEMM before hc's first write)
    ushort* xc = hc;

    // 1) convert x to bf16; all 7 weight transposes in one dispatch
    cvt_x_kernel<<<(N_NODES * CH / 4 + 255) / 256, 256, 0, stream>>>(x, xc, N_NODES * CH / 4);
    transpose_cvt_all<<<dim3(24, 24, 7), dim3(32, 8), 0, stream>>>(w_in, Wl, Wr, wt_in, wt_l);

    // 2) CSR by dst + graph segments
    int nb = (N_NODES + 255) / 256, eb = (N_EDGES + 255) / 256;
    hipMemsetAsync(deg, 0, (size_t)N_NODES * 4, stream);
    hipMemsetAsync(gcount, 0, 256 * 4, stream);
    count_both_kernel<<<eb, 256, 0, stream>>>(ei + N_EDGES, deg, N_EDGES, batch, gcount, N_NODES);
    scan_kernel<<<1, 1024, 0, stream>>>(deg, rowptr, N_NODES);
    selfloop_kernel<<<nb, 256, 0, stream>>>(rowptr, csrc, cursor, N_NODES);
    scatter_kernel<<<eb, 256, 0, stream>>>(ei, ei + N_EDGES, cursor, csrc, N_EDGES);
    gscan_kernel<<<1, 256, 0, stream>>>(gcount, gstart);

    // 3) h0 = x @ w_in + b_in
    gemm_bf16_kernel<<<dim3(157, 6), 256, 0, stream>>>(
        xc, CH, wt_in, b_in, b_in, CH, h0, CH, N_NODES);

    // 4) three GATv2 layers
    for (int l = 0; l < 3; ++l) {
        const ushort* hprev = (l == 0) ? h0 : (hc + (size_t)(l - 1) * CH);
        int ldh = (l == 0) ? CH : CH3;
        gemm_bf16_kernel<<<dim3(157, 12), 256, 0, stream>>>(
            hprev, ldh, wt_l + (size_t)l * 1536 * CH,
            bl + (size_t)l * CH, br + (size_t)l * CH, CH,
            xlxr, 1536, N_NODES);
        gat_node_kernel<<<N_NODES / 4, 256, 0, stream>>>(
            xlxr, hprev, ldh, rowptr, csrc,
            att + (size_t)l * CH, gbias + (size_t)l * CH,
            lnw + (size_t)l * CH, lnb + (size_t)l * CH,
            hc + (size_t)l * CH, N_NODES);
    }

    // 5) pool + head (all f32, f32 output)
    pool_kernel<<<dim3(NGRAPH, CH3 / 256), 256, 0, stream>>>(hc, gstart, pooled);
    head_kernel<<<NGRAPH, 256, 0, stream>>>(pooled, olnw, olnb, wout, bout, (float*)d_out);
}